// Round 6
// baseline (493.699 us; speedup 1.0000x reference)
//
#include <hip/hip_runtime.h>
#include <math.h>

// GCN forward: 3x GCNConv (128->4->4->2) + classifier (2->4).
// Edges partitioned once per call into 256-node dst-buckets (packed int:
// dl<<17|src). Per-layer aggregation: NB*SEG blocks each aggregate a bucket
// SEGMENT into LDS (transposed, padded), 8-edge-wide inner loop (2x int4
// packed loads + 8 independent gathers in flight) to hide gather latency;
// combine kernel sums partials + fused finalize. Zero global atomics.

#define CHUNK 8192
#define NSEG 8

// Pass A: per-block histogram of dst-buckets (bucket = dst>>8), transposed.
__global__ void k_hist(const int* __restrict__ dst, int* __restrict__ hbT,
                       int NB, int G, int e) {
    __shared__ int hist[512];
    int g = blockIdx.x;
    for (int b = threadIdx.x; b < NB; b += 256) hist[b] = 0;
    __syncthreads();
    int i0 = g * CHUNK, i1 = min(i0 + CHUNK, e);
    for (int i = i0 + threadIdx.x; i < i1; i += 256)
        atomicAdd(&hist[dst[i] >> 8], 1);
    __syncthreads();
    for (int b = threadIdx.x; b < NB; b += 256)
        hbT[(size_t)b * G + g] = hist[b];
}

// Scan A: one block per bucket; exclusive scan of hbT[b][0..G) in place.
__global__ void k_scanA(int* __restrict__ hbT, int* __restrict__ btot, int G) {
    __shared__ int part[256];
    int b = blockIdx.x;
    int t = threadIdx.x;
    int* row = hbT + (size_t)b * G;
    int C = (G + 255) / 256;
    int lo = t * C, hi = min(lo + C, G);
    int s = 0;
    for (int i = lo; i < hi; i++) s += row[i];
    part[t] = s;
    __syncthreads();
#pragma unroll
    for (int off = 1; off < 256; off <<= 1) {
        int u = (t >= off) ? part[t - off] : 0;
        __syncthreads();
        part[t] += u;
        __syncthreads();
    }
    int run = part[t] - s;
    for (int i = lo; i < hi; i++) {
        int v = row[i];
        row[i] = run;
        run += v;
    }
    if (t == 255) btot[b] = part[255];
}

// Scan B: exclusive scan of the NB bucket totals (NB <= 512).
__global__ void k_scanB(const int* __restrict__ btot, int* __restrict__ bstart,
                        int NB, int e) {
    __shared__ int part[512];
    int t = threadIdx.x;
    int v = (t < NB) ? btot[t] : 0;
    part[t] = v;
    __syncthreads();
#pragma unroll
    for (int off = 1; off < 512; off <<= 1) {
        int u = (t >= off) ? part[t - off] : 0;
        __syncthreads();
        part[t] += u;
        __syncthreads();
    }
    if (t < NB) bstart[t] = part[t] - v;
    if (t == 0) bstart[NB] = e;
}

// Pass B: partition edges into buckets. packed = (dst&255)<<17 | src.
__global__ void k_part(const int* __restrict__ src, const int* __restrict__ dst,
                       const int* __restrict__ hbT, const int* __restrict__ bstart,
                       int* __restrict__ packed, int NB, int G, int e) {
    __shared__ int cur[512];
    int g = blockIdx.x;
    for (int b = threadIdx.x; b < NB; b += 256)
        cur[b] = hbT[(size_t)b * G + g] + bstart[b];
    __syncthreads();
    int i0 = g * CHUNK, i1 = min(i0 + CHUNK, e);
    for (int i = i0 + threadIdx.x; i < i1; i += 256) {
        int d = dst[i];
        int s = src[i];
        int pos = atomicAdd(&cur[d >> 8], 1);
        packed[pos] = ((d & 255) << 17) | s;
    }
}

// Compute segment range [lo,hi) of bucket b, plus 8-aligned vector region.
__device__ __forceinline__ void seg_range(const int* bstart, int blk, int SEG,
                                          int& b, int& lo, int& hi) {
    b = blk / SEG;
    int s = blk - b * SEG;
    int j0 = bstart[b], len = bstart[b + 1] - j0;
    lo = j0 + (int)((long long)len * s / SEG);
    hi = j0 + (int)((long long)len * (s + 1) / SEG);
}

// Segmented degree histogram, 8-wide.
__global__ void k_degseg(const int* __restrict__ bstart, const int* __restrict__ packed,
                         int* __restrict__ pdeg, int SEG) {
    __shared__ int cnt[256];
    int tid = threadIdx.x;
    cnt[tid] = 0;
    __syncthreads();
    int b, lo, hi;
    seg_range(bstart, blockIdx.x, SEG, b, lo, hi);
    int loA = (lo + 3) & ~3;
    if (loA > hi) loA = hi;
    int vend = loA + ((hi - loA) & ~7);
    for (int j = lo + tid; j < loA; j += 256) atomicAdd(&cnt[packed[j] >> 17], 1);
    for (int base = loA + tid * 8; base < vend; base += 2048) {
        int4 wa = *reinterpret_cast<const int4*>(packed + base);
        int4 wb = *reinterpret_cast<const int4*>(packed + base + 4);
        atomicAdd(&cnt[wa.x >> 17], 1); atomicAdd(&cnt[wa.y >> 17], 1);
        atomicAdd(&cnt[wa.z >> 17], 1); atomicAdd(&cnt[wa.w >> 17], 1);
        atomicAdd(&cnt[wb.x >> 17], 1); atomicAdd(&cnt[wb.y >> 17], 1);
        atomicAdd(&cnt[wb.z >> 17], 1); atomicAdd(&cnt[wb.w >> 17], 1);
    }
    for (int j = vend + tid; j < hi; j += 256) atomicAdd(&cnt[packed[j] >> 17], 1);
    __syncthreads();
    pdeg[(size_t)blockIdx.x * 256 + tid] = cnt[tid];
}

__global__ void k_degcomb(const int* __restrict__ pdeg, float* __restrict__ dinv,
                          int n, int SEG) {
    int b = blockIdx.x, tid = threadIdx.x;
    int node = (b << 8) + tid;
    if (node >= n) return;
    const int* P = pdeg + (size_t)b * SEG * 256 + tid;
    int c = 0;
    for (int s = 0; s < SEG; s++) c += P[s * 256];
    dinv[node] = 1.0f / sqrtf((float)(c + 1));
}

// Layer 1 GEMV: one wave per node. hs = (x @ W1) * dinv.
__global__ void k_mm1(const float* __restrict__ x, const float* __restrict__ W,
                      const float* __restrict__ dinv, float* __restrict__ hs, int n) {
    int gid = blockIdx.x * blockDim.x + threadIdx.x;
    int node = gid >> 6;
    int lane = threadIdx.x & 63;
    if (node >= n) return;
    const float2 xv = *reinterpret_cast<const float2*>(x + (size_t)node * 128 + lane * 2);
    const float4 w0 = *reinterpret_cast<const float4*>(W + (lane * 2) * 4);
    const float4 w1 = *reinterpret_cast<const float4*>(W + (lane * 2 + 1) * 4);
    float a0 = xv.x * w0.x + xv.y * w1.x;
    float a1 = xv.x * w0.y + xv.y * w1.y;
    float a2 = xv.x * w0.z + xv.y * w1.z;
    float a3 = xv.x * w0.w + xv.y * w1.w;
#pragma unroll
    for (int m = 32; m >= 1; m >>= 1) {
        a0 += __shfl_xor(a0, m);
        a1 += __shfl_xor(a1, m);
        a2 += __shfl_xor(a2, m);
        a3 += __shfl_xor(a3, m);
    }
    if (lane == 0) {
        float di = dinv[node];
        *reinterpret_cast<float4*>(hs + (size_t)node * 4) =
            make_float4(a0 * di, a1 * di, a2 * di, a3 * di);
    }
}

// Segment aggregate, 4-wide hs, 8-edge MLP inner loop.
__global__ void k_seg4(const int* __restrict__ bstart, const int* __restrict__ packed,
                       const float* __restrict__ hs, float* __restrict__ partial,
                       int SEG) {
    __shared__ float agg[4 * 260];
    int tid = threadIdx.x;
    for (int k = tid; k < 4 * 260; k += 256) agg[k] = 0.0f;
    __syncthreads();
    int b, lo, hi;
    seg_range(bstart, blockIdx.x, SEG, b, lo, hi);
    int loA = (lo + 3) & ~3;
    if (loA > hi) loA = hi;
    int vend = loA + ((hi - loA) & ~7);

#define DO_EDGE4(w) { int sr = (w) & 0x1FFFF; int dl = (w) >> 17; \
        float4 v = *reinterpret_cast<const float4*>(hs + (size_t)sr * 4); \
        atomicAdd(&agg[0 * 260 + dl], v.x); atomicAdd(&agg[1 * 260 + dl], v.y); \
        atomicAdd(&agg[2 * 260 + dl], v.z); atomicAdd(&agg[3 * 260 + dl], v.w); }

    for (int j = lo + tid; j < loA; j += 256) { int w = packed[j]; DO_EDGE4(w); }
    for (int base = loA + tid * 8; base < vend; base += 2048) {
        int4 wa = *reinterpret_cast<const int4*>(packed + base);
        int4 wb = *reinterpret_cast<const int4*>(packed + base + 4);
        // 8 independent gathers issued before any LDS use
        const float4 v0 = *reinterpret_cast<const float4*>(hs + (size_t)(wa.x & 0x1FFFF) * 4);
        const float4 v1 = *reinterpret_cast<const float4*>(hs + (size_t)(wa.y & 0x1FFFF) * 4);
        const float4 v2 = *reinterpret_cast<const float4*>(hs + (size_t)(wa.z & 0x1FFFF) * 4);
        const float4 v3 = *reinterpret_cast<const float4*>(hs + (size_t)(wa.w & 0x1FFFF) * 4);
        const float4 v4 = *reinterpret_cast<const float4*>(hs + (size_t)(wb.x & 0x1FFFF) * 4);
        const float4 v5 = *reinterpret_cast<const float4*>(hs + (size_t)(wb.y & 0x1FFFF) * 4);
        const float4 v6 = *reinterpret_cast<const float4*>(hs + (size_t)(wb.z & 0x1FFFF) * 4);
        const float4 v7 = *reinterpret_cast<const float4*>(hs + (size_t)(wb.w & 0x1FFFF) * 4);
        int d0 = wa.x >> 17, d1 = wa.y >> 17, d2 = wa.z >> 17, d3 = wa.w >> 17;
        int d4 = wb.x >> 17, d5 = wb.y >> 17, d6 = wb.z >> 17, d7 = wb.w >> 17;
        atomicAdd(&agg[0 * 260 + d0], v0.x); atomicAdd(&agg[1 * 260 + d0], v0.y);
        atomicAdd(&agg[2 * 260 + d0], v0.z); atomicAdd(&agg[3 * 260 + d0], v0.w);
        atomicAdd(&agg[0 * 260 + d1], v1.x); atomicAdd(&agg[1 * 260 + d1], v1.y);
        atomicAdd(&agg[2 * 260 + d1], v1.z); atomicAdd(&agg[3 * 260 + d1], v1.w);
        atomicAdd(&agg[0 * 260 + d2], v2.x); atomicAdd(&agg[1 * 260 + d2], v2.y);
        atomicAdd(&agg[2 * 260 + d2], v2.z); atomicAdd(&agg[3 * 260 + d2], v2.w);
        atomicAdd(&agg[0 * 260 + d3], v3.x); atomicAdd(&agg[1 * 260 + d3], v3.y);
        atomicAdd(&agg[2 * 260 + d3], v3.z); atomicAdd(&agg[3 * 260 + d3], v3.w);
        atomicAdd(&agg[0 * 260 + d4], v4.x); atomicAdd(&agg[1 * 260 + d4], v4.y);
        atomicAdd(&agg[2 * 260 + d4], v4.z); atomicAdd(&agg[3 * 260 + d4], v4.w);
        atomicAdd(&agg[0 * 260 + d5], v5.x); atomicAdd(&agg[1 * 260 + d5], v5.y);
        atomicAdd(&agg[2 * 260 + d5], v5.z); atomicAdd(&agg[3 * 260 + d5], v5.w);
        atomicAdd(&agg[0 * 260 + d6], v6.x); atomicAdd(&agg[1 * 260 + d6], v6.y);
        atomicAdd(&agg[2 * 260 + d6], v6.z); atomicAdd(&agg[3 * 260 + d6], v6.w);
        atomicAdd(&agg[0 * 260 + d7], v7.x); atomicAdd(&agg[1 * 260 + d7], v7.y);
        atomicAdd(&agg[2 * 260 + d7], v7.z); atomicAdd(&agg[3 * 260 + d7], v7.w);
    }
    for (int j = vend + tid; j < hi; j += 256) { int w = packed[j]; DO_EDGE4(w); }
#undef DO_EDGE4
    __syncthreads();
    float* P = partial + (size_t)blockIdx.x * 1024;
    for (int k = tid; k < 1024; k += 256)
        P[k] = agg[(k >> 8) * 260 + (k & 255)];
}

// Segment aggregate, 2-wide hs, 8-edge MLP inner loop.
__global__ void k_seg2(const int* __restrict__ bstart, const int* __restrict__ packed,
                       const float* __restrict__ hs, float* __restrict__ partial,
                       int SEG) {
    __shared__ float agg[2 * 260];
    int tid = threadIdx.x;
    for (int k = tid; k < 2 * 260; k += 256) agg[k] = 0.0f;
    __syncthreads();
    int b, lo, hi;
    seg_range(bstart, blockIdx.x, SEG, b, lo, hi);
    int loA = (lo + 3) & ~3;
    if (loA > hi) loA = hi;
    int vend = loA + ((hi - loA) & ~7);

#define DO_EDGE2(w) { int sr = (w) & 0x1FFFF; int dl = (w) >> 17; \
        float2 v = *reinterpret_cast<const float2*>(hs + (size_t)sr * 2); \
        atomicAdd(&agg[0 * 260 + dl], v.x); atomicAdd(&agg[1 * 260 + dl], v.y); }

    for (int j = lo + tid; j < loA; j += 256) { int w = packed[j]; DO_EDGE2(w); }
    for (int base = loA + tid * 8; base < vend; base += 2048) {
        int4 wa = *reinterpret_cast<const int4*>(packed + base);
        int4 wb = *reinterpret_cast<const int4*>(packed + base + 4);
        const float2 v0 = *reinterpret_cast<const float2*>(hs + (size_t)(wa.x & 0x1FFFF) * 2);
        const float2 v1 = *reinterpret_cast<const float2*>(hs + (size_t)(wa.y & 0x1FFFF) * 2);
        const float2 v2 = *reinterpret_cast<const float2*>(hs + (size_t)(wa.z & 0x1FFFF) * 2);
        const float2 v3 = *reinterpret_cast<const float2*>(hs + (size_t)(wa.w & 0x1FFFF) * 2);
        const float2 v4 = *reinterpret_cast<const float2*>(hs + (size_t)(wb.x & 0x1FFFF) * 2);
        const float2 v5 = *reinterpret_cast<const float2*>(hs + (size_t)(wb.y & 0x1FFFF) * 2);
        const float2 v6 = *reinterpret_cast<const float2*>(hs + (size_t)(wb.z & 0x1FFFF) * 2);
        const float2 v7 = *reinterpret_cast<const float2*>(hs + (size_t)(wb.w & 0x1FFFF) * 2);
        int d0 = wa.x >> 17, d1 = wa.y >> 17, d2 = wa.z >> 17, d3 = wa.w >> 17;
        int d4 = wb.x >> 17, d5 = wb.y >> 17, d6 = wb.z >> 17, d7 = wb.w >> 17;
        atomicAdd(&agg[0 * 260 + d0], v0.x); atomicAdd(&agg[1 * 260 + d0], v0.y);
        atomicAdd(&agg[0 * 260 + d1], v1.x); atomicAdd(&agg[1 * 260 + d1], v1.y);
        atomicAdd(&agg[0 * 260 + d2], v2.x); atomicAdd(&agg[1 * 260 + d2], v2.y);
        atomicAdd(&agg[0 * 260 + d3], v3.x); atomicAdd(&agg[1 * 260 + d3], v3.y);
        atomicAdd(&agg[0 * 260 + d4], v4.x); atomicAdd(&agg[1 * 260 + d4], v4.y);
        atomicAdd(&agg[0 * 260 + d5], v5.x); atomicAdd(&agg[1 * 260 + d5], v5.y);
        atomicAdd(&agg[0 * 260 + d6], v6.x); atomicAdd(&agg[1 * 260 + d6], v6.y);
        atomicAdd(&agg[0 * 260 + d7], v7.x); atomicAdd(&agg[1 * 260 + d7], v7.y);
    }
    for (int j = vend + tid; j < hi; j += 256) { int w = packed[j]; DO_EDGE2(w); }
#undef DO_EDGE2
    __syncthreads();
    float* P = partial + (size_t)blockIdx.x * 512;
    for (int k = tid; k < 512; k += 256)
        P[k] = agg[(k >> 8) * 260 + (k & 255)];
}

// Combine partials + finalize: h = tanh((agg+hs)*dinv + b); hsn = (h@Wn)*dinv.
template <int FOUT>
__global__ void k_comb4(const float* __restrict__ partial, const float* __restrict__ hs,
                        const float* __restrict__ dinv, const float* __restrict__ b_,
                        const float* __restrict__ Wn, float* __restrict__ hsn,
                        int n, int SEG) {
    int b = blockIdx.x, tid = threadIdx.x;
    int node = (b << 8) + tid;
    if (node >= n) return;
    const float* P = partial + (size_t)b * SEG * 1024 + tid;
    float a0 = 0.f, a1 = 0.f, a2 = 0.f, a3 = 0.f;
    for (int s = 0; s < SEG; s++) {
        const float* q = P + s * 1024;
        a0 += q[0]; a1 += q[256]; a2 += q[512]; a3 += q[768];
    }
    float4 sv = *reinterpret_cast<const float4*>(hs + (size_t)node * 4);
    float di = dinv[node];
    float h0 = tanhf((a0 + sv.x) * di + b_[0]);
    float h1 = tanhf((a1 + sv.y) * di + b_[1]);
    float h2 = tanhf((a2 + sv.z) * di + b_[2]);
    float h3 = tanhf((a3 + sv.w) * di + b_[3]);
    float o[FOUT];
#pragma unroll
    for (int j = 0; j < FOUT; j++) {
        o[j] = (h0 * Wn[0 * FOUT + j] + h1 * Wn[1 * FOUT + j] +
                h2 * Wn[2 * FOUT + j] + h3 * Wn[3 * FOUT + j]) * di;
    }
    if constexpr (FOUT == 4) {
        *reinterpret_cast<float4*>(hsn + (size_t)node * 4) =
            make_float4(o[0], o[1], o[2], o[3]);
    } else {
        *reinterpret_cast<float2*>(hsn + (size_t)node * 2) = make_float2(o[0], o[1]);
    }
}

// Final combine: h3 = tanh(...) -> hout; out = h3@Wc + bc.
__global__ void k_comb3(const float* __restrict__ partial, const float* __restrict__ hs,
                        const float* __restrict__ dinv, const float* __restrict__ b3,
                        const float* __restrict__ Wc, const float* __restrict__ bc,
                        float* __restrict__ out, float* __restrict__ hout,
                        int n, int SEG) {
    int b = blockIdx.x, tid = threadIdx.x;
    int node = (b << 8) + tid;
    if (node >= n) return;
    const float* P = partial + (size_t)b * SEG * 512 + tid;
    float a0 = 0.f, a1 = 0.f;
    for (int s = 0; s < SEG; s++) {
        const float* q = P + s * 512;
        a0 += q[0]; a1 += q[256];
    }
    float2 sv = *reinterpret_cast<const float2*>(hs + (size_t)node * 2);
    float di = dinv[node];
    float h0 = tanhf((a0 + sv.x) * di + b3[0]);
    float h1 = tanhf((a1 + sv.y) * di + b3[1]);
    *reinterpret_cast<float2*>(hout + (size_t)node * 2) = make_float2(h0, h1);
    float4 o;
    o.x = h0 * Wc[0] + h1 * Wc[4] + bc[0];
    o.y = h0 * Wc[1] + h1 * Wc[5] + bc[1];
    o.z = h0 * Wc[2] + h1 * Wc[6] + bc[2];
    o.w = h0 * Wc[3] + h1 * Wc[7] + bc[3];
    *reinterpret_cast<float4*>(out + (size_t)node * 4) = o;
}

extern "C" void kernel_launch(void* const* d_in, const int* in_sizes, int n_in,
                              void* d_out, int out_size, void* d_ws, size_t ws_size,
                              hipStream_t stream) {
    const float* x  = (const float*)d_in[0];
    const int*  ei  = (const int*)d_in[1];
    const float* W1 = (const float*)d_in[2];
    const float* b1 = (const float*)d_in[3];
    const float* W2 = (const float*)d_in[4];
    const float* b2 = (const float*)d_in[5];
    const float* W3 = (const float*)d_in[6];
    const float* b3 = (const float*)d_in[7];
    const float* Wc = (const float*)d_in[8];
    const float* bc = (const float*)d_in[9];

    const int n = in_sizes[0] / 128;
    const int e = in_sizes[1] / 2;
    const int* src = ei;
    const int* dst = ei + e;

    const int NB = (n + 255) >> 8;            // dst buckets (256 nodes each)
    const int G  = (e + CHUNK - 1) / CHUNK;   // edge chunks

    const size_t MB = 1024 * 1024;
    char* ws = (char*)d_ws;
    float* dinv    = (float*)(ws + 0 * MB);   // n floats
    float* hsA     = (float*)(ws + 1 * MB);   // n*4 floats
    float* hsB     = (float*)(ws + 3 * MB);   // n*4 floats
    int*   hbT     = (int*)  (ws + 5 * MB);   // NB*G ints (~1.3 MB)
    int*   btot    = (int*)  (ws + 7 * MB);   // NB ints
    int*   bstart  = (int*)  (ws + 7 * MB + 4096);
    int*   packed  = (int*)  (ws + 8 * MB);   // e ints (25.6 MB)
    float* partial = (float*)(ws + 34 * MB);  // SEG*NB*1024 floats

    int SEG = NSEG;
    while (SEG > 1 && 34 * MB + (size_t)SEG * NB * 1024 * 4 > ws_size) SEG >>= 1;

    float* out  = (float*)d_out;
    float* hout = out + (size_t)n * 4;

    // Build bucketed edge list (once; reused by all 3 layers)
    k_hist<<<G, 256, 0, stream>>>(dst, hbT, NB, G, e);
    k_scanA<<<NB, 256, 0, stream>>>(hbT, btot, G);
    k_scanB<<<1, 512, 0, stream>>>(btot, bstart, NB, e);
    k_part<<<G, 256, 0, stream>>>(src, dst, hbT, bstart, packed, NB, G, e);

    // degree -> dinv (segmented)
    k_degseg<<<NB * SEG, 256, 0, stream>>>(bstart, packed, (int*)partial, SEG);
    k_degcomb<<<NB, 256, 0, stream>>>((const int*)partial, dinv, n, SEG);

    // Layer 1 GEMV: hsA = (x @ W1) * dinv
    k_mm1<<<(n + 3) / 4, 256, 0, stream>>>(x, W1, dinv, hsA, n);

    // Layer 1: aggregate + finalize (fused W2)
    k_seg4<<<NB * SEG, 256, 0, stream>>>(bstart, packed, hsA, partial, SEG);
    k_comb4<4><<<NB, 256, 0, stream>>>(partial, hsA, dinv, b1, W2, hsB, n, SEG);
    // Layer 2: aggregate + finalize (fused W3)
    k_seg4<<<NB * SEG, 256, 0, stream>>>(bstart, packed, hsB, partial, SEG);
    k_comb4<2><<<NB, 256, 0, stream>>>(partial, hsB, dinv, b2, W3, hsA, n, SEG);
    // Layer 3: aggregate + finalize (fused classifier)
    k_seg2<<<NB * SEG, 256, 0, stream>>>(bstart, packed, hsA, partial, SEG);
    k_comb3<<<NB, 256, 0, stream>>>(partial, hsA, dinv, b3, Wc, bc, out, hout, n, SEG);

    (void)n_in; (void)out_size; (void)ws_size;
}